// Round 5
// baseline (118.505 us; speedup 1.0000x reference)
//
#include <hip/hip_runtime.h>
#include <hip/hip_bf16.h>
#include <math.h>

// B=2, S=160, H=768, C=5 ; M = B*S = 320, N = C*H = 3840, K = H = 768

typedef __attribute__((ext_vector_type(8))) short bf16x8;
typedef __attribute__((ext_vector_type(4))) float f32x4;

__device__ __forceinline__ unsigned short f2bf(float f) {
    union { float f; unsigned u; } v; v.f = f;
    unsigned r = (v.u + 0x7FFFu + ((v.u >> 16) & 1u)) >> 16;
    return (unsigned short)r;
}

// 64x64 output tile per block, BK=32, 4 waves each computing a 32x32 quadrant
// via v_mfma_f32_16x16x32_bf16. Epilogue stores tanh(acc+bias), clamped to
// +-0.999999 so the downstream tanh-addition identity is NaN-safe.
__global__ __launch_bounds__(256) void proj_gemm_mfma(
    const float* __restrict__ A,     // [320, 768]
    const float* __restrict__ Wp,    // [768, 3840]
    const float* __restrict__ bp,    // [3840]
    const float* __restrict__ Wa,
    const float* __restrict__ ba,
    float* __restrict__ hp,          // [320, 3840]  (tanh of projection)
    float* __restrict__ ha)
{
    const int which = blockIdx.z;
    const float* W    = which ? Wa : Wp;
    const float* bias = which ? ba : bp;
    float* out        = which ? ha : hp;

    const int n0 = blockIdx.x * 64;
    const int m0 = blockIdx.y * 64;
    const int tid  = threadIdx.x;
    const int lane = tid & 63;
    const int w    = tid >> 6;

    __shared__ __attribute__((aligned(16))) short As[64][40]; // [m][k], pad 32->40
    __shared__ __attribute__((aligned(16))) short Bs[64][40]; // [n][k] (W transposed)

    f32x4 acc[2][2] = {};

    // staging indices
    const int ra = tid >> 2;          // 0..63 : A row
    const int ka = (tid & 3) * 8;     // 0,8,16,24 : A k-offset
    const int nb = tid & 63;          // 0..63 : B col (n), lane-contiguous
    const int kb = (tid >> 6) * 8;    // 0,8,16,24 : B k-offset

    // fragment indices
    const int wm = (w & 1) * 32;
    const int wn = (w >> 1) * 32;
    const int fr = lane & 15;
    const int fk = (lane >> 4) * 8;

    const float* Arow = A + (size_t)(m0 + ra) * 768 + ka;

    for (int k0 = 0; k0 < 768; k0 += 32) {
        // issue global loads early (in flight across the barrier)
        float4 a0 = *reinterpret_cast<const float4*>(Arow + k0);
        float4 a1 = *reinterpret_cast<const float4*>(Arow + k0 + 4);
        float bvals[8];
        #pragma unroll
        for (int j = 0; j < 8; ++j)
            bvals[j] = W[(size_t)(k0 + kb + j) * 3840 + n0 + nb];

        __syncthreads();  // previous iteration's fragment reads complete

        bf16x8 av;
        av[0] = f2bf(a0.x); av[1] = f2bf(a0.y); av[2] = f2bf(a0.z); av[3] = f2bf(a0.w);
        av[4] = f2bf(a1.x); av[5] = f2bf(a1.y); av[6] = f2bf(a1.z); av[7] = f2bf(a1.w);
        *reinterpret_cast<bf16x8*>(&As[ra][ka]) = av;

        bf16x8 bv;
        #pragma unroll
        for (int j = 0; j < 8; ++j) bv[j] = f2bf(bvals[j]);
        *reinterpret_cast<bf16x8*>(&Bs[nb][kb]) = bv;

        __syncthreads();

        bf16x8 af0 = *reinterpret_cast<const bf16x8*>(&As[wm + fr][fk]);
        bf16x8 af1 = *reinterpret_cast<const bf16x8*>(&As[wm + 16 + fr][fk]);
        bf16x8 bf0 = *reinterpret_cast<const bf16x8*>(&Bs[wn + fr][fk]);
        bf16x8 bf1 = *reinterpret_cast<const bf16x8*>(&Bs[wn + 16 + fr][fk]);

        acc[0][0] = __builtin_amdgcn_mfma_f32_16x16x32_bf16(af0, bf0, acc[0][0], 0, 0, 0);
        acc[0][1] = __builtin_amdgcn_mfma_f32_16x16x32_bf16(af0, bf1, acc[0][1], 0, 0, 0);
        acc[1][0] = __builtin_amdgcn_mfma_f32_16x16x32_bf16(af1, bf0, acc[1][0], 0, 0, 0);
        acc[1][1] = __builtin_amdgcn_mfma_f32_16x16x32_bf16(af1, bf1, acc[1][1], 0, 0, 0);
    }

    // C/D layout: col = lane&15, row = (lane>>4)*4 + reg
    #pragma unroll
    for (int j = 0; j < 2; ++j) {
        const int col = n0 + wn + j * 16 + fr;
        const float bb = bias[col];
        #pragma unroll
        for (int i = 0; i < 2; ++i) {
            #pragma unroll
            for (int r = 0; r < 4; ++r) {
                const int row = m0 + wm + i * 16 + (lane >> 4) * 4 + r;
                float t = tanhf(acc[i][j][r] + bb);
                t = __builtin_amdgcn_fmed3f(t, -0.999999f, 0.999999f);
                out[(size_t)row * 3840 + col] = t;
            }
        }
    }
}

// score[b,p,c,a] = sum_h tanh(hp+ha)*w = sum_h ((tp+ta)/(1+tp*ta))*w  (exact identity)
// 32x32 (p,a) tile per block, 2x2 outputs per thread.
__global__ __launch_bounds__(256) void scores_kernel(
    const float* __restrict__ tp_g,  // [320, 3840]  tanh(hp)
    const float* __restrict__ ta_g,  // [320, 3840]  tanh(ha)
    const float* __restrict__ w_out, // [768]
    const int*  __restrict__ mask,   // [B,S,C,S] as int32
    float* __restrict__ out)         // [B,S,C,S]
{
    const int at0 = blockIdx.x * 32; // 0..4
    const int pt0 = blockIdx.y * 32; // 0..4
    const int bc  = blockIdx.z;      // 0..9
    const int b = bc / 5, c = bc % 5;

    const int tid = threadIdx.x;
    const int tx = tid & 15;         // a index
    const int ty = tid >> 4;         // p index

    __shared__ __attribute__((aligned(16))) float w_s[768];
    __shared__ __attribute__((aligned(16))) float hp_s[32][260]; // 256 + 4 pad
    __shared__ __attribute__((aligned(16))) float ha_s[32][260];

    if (tid < 192) {
        *reinterpret_cast<float4*>(&w_s[tid * 4]) =
            *reinterpret_cast<const float4*>(&w_out[tid * 4]);
    }

    const float* hp_base = tp_g + (size_t)(b * 160 + pt0) * 3840 + c * 768;
    const float* ha_base = ta_g + (size_t)(b * 160 + at0) * 3840 + c * 768;

    float acc00 = 0.f, acc01 = 0.f, acc10 = 0.f, acc11 = 0.f;

    for (int k0 = 0; k0 < 768; k0 += 256) {
        __syncthreads();   // protects w_s (iter 0) and hp_s/ha_s reuse
        #pragma unroll
        for (int i = 0; i < 8; ++i) {
            int f4  = i * 256 + tid;       // 0..2047
            int row = f4 >> 6;             // 32 rows, 64 float4 each
            int col = (f4 & 63) * 4;
            *reinterpret_cast<float4*>(&hp_s[row][col]) =
                *reinterpret_cast<const float4*>(&hp_base[(size_t)row * 3840 + k0 + col]);
            *reinterpret_cast<float4*>(&ha_s[row][col]) =
                *reinterpret_cast<const float4*>(&ha_base[(size_t)row * 3840 + k0 + col]);
        }
        __syncthreads();
        #pragma unroll 4
        for (int j = 0; j < 64; ++j) {
            float4 w4 = *reinterpret_cast<const float4*>(&w_s[k0 + j * 4]);
            float4 p0 = *reinterpret_cast<const float4*>(&hp_s[ty     ][j * 4]);
            float4 p1 = *reinterpret_cast<const float4*>(&hp_s[ty + 16][j * 4]);
            float4 a0 = *reinterpret_cast<const float4*>(&ha_s[tx     ][j * 4]);
            float4 a1 = *reinterpret_cast<const float4*>(&ha_s[tx + 16][j * 4]);

#define TERM(ACC, P, A, W) \
            { float s_ = (P) + (A); \
              float d_ = fmaf((P), (A), 1.f); \
              ACC = fmaf(s_ * __builtin_amdgcn_rcpf(d_), (W), ACC); }
#define LANE(PX, AX, W) \
            TERM(acc00, p0.PX, a0.AX, W) \
            TERM(acc01, p0.PX, a1.AX, W) \
            TERM(acc10, p1.PX, a0.AX, W) \
            TERM(acc11, p1.PX, a1.AX, W)

            LANE(x, x, w4.x)
            LANE(y, y, w4.y)
            LANE(z, z, w4.z)
            LANE(w, w, w4.w)
#undef LANE
#undef TERM
        }
    }

    #pragma unroll
    for (int pi = 0; pi < 2; ++pi) {
        #pragma unroll
        for (int ai = 0; ai < 2; ++ai) {
            const int p = pt0 + pi * 16 + ty;
            const int a = at0 + ai * 16 + tx;
            const size_t idx = ((size_t)(b * 160 + p) * 5 + c) * 160 + a;
            float v = pi ? (ai ? acc11 : acc10) : (ai ? acc01 : acc00);
            out[idx] = v + (mask[idx] ? 0.f : -1024.f);
        }
    }
}

// one wave per (b,p,c) row of 160 args
__global__ __launch_bounds__(256) void loss_kernel(
    const float* __restrict__ scores,  // [1600,160]
    const int*  __restrict__ target,
    float* __restrict__ acc)           // acc[0]=sum(-logsm*t), acc[1]=sum(t)
{
    const int lane = threadIdx.x & 63;
    const int wid  = threadIdx.x >> 6;
    const int row  = blockIdx.x * 4 + wid;  // 0..1599
    const float* x = scores + (size_t)row * 160;
    const int*  t  = target + (size_t)row * 160;

    float x0 = x[lane];
    float x1 = x[lane + 64];
    float x2 = (lane < 32) ? x[lane + 128] : -INFINITY;

    float m = fmaxf(fmaxf(x0, x1), x2);
    #pragma unroll
    for (int o = 32; o >= 1; o >>= 1)
        m = fmaxf(m, __shfl_xor(m, o));

    float s = __expf(x0 - m) + __expf(x1 - m) + ((lane < 32) ? __expf(x2 - m) : 0.f);
    #pragma unroll
    for (int o = 32; o >= 1; o >>= 1)
        s += __shfl_xor(s, o);
    float lse = logf(s) + m;

    int t0 = t[lane], t1 = t[lane + 64];
    int t2 = (lane < 32) ? t[lane + 128] : 0;
    float pl = (float)t0 * (lse - x0) + (float)t1 * (lse - x1)
             + ((lane < 32 && t2) ? (float)t2 * (lse - x2) : 0.f);
    float pts = (float)(t0 + t1 + t2);
    #pragma unroll
    for (int o = 32; o >= 1; o >>= 1) {
        pl  += __shfl_xor(pl, o);
        pts += __shfl_xor(pts, o);
    }
    if (lane == 0) {
        atomicAdd(&acc[0], pl);
        atomicAdd(&acc[1], pts);
    }
}

__global__ void finalize_kernel(const float* __restrict__ acc, float* __restrict__ out0)
{
    out0[0] = acc[0] / (acc[1] + 1e-6f);
}

extern "C" void kernel_launch(void* const* d_in, const int* in_sizes, int n_in,
                              void* d_out, int out_size, void* d_ws, size_t ws_size,
                              hipStream_t stream) {
    const float* seq   = (const float*)d_in[0];
    const float* w_prd = (const float*)d_in[1];
    const float* b_prd = (const float*)d_in[2];
    const float* w_arg = (const float*)d_in[3];
    const float* b_arg = (const float*)d_in[4];
    const float* w_out = (const float*)d_in[5];
    const int*   mask  = (const int*)d_in[6];
    const int*   targ  = (const int*)d_in[7];

    float* out = (float*)d_out;          // out[0]=loss, out+1 = scores [2,160,5,160]
    float* hp  = (float*)d_ws;           // [320,3840]  tanh(h_p)
    float* ha  = hp + 320 * 3840;        // [320,3840]  tanh(h_a)
    float* acc = ha + 320 * 3840;        // [2]

    hipMemsetAsync(acc, 0, 2 * sizeof(float), stream);

    dim3 g1(60, 5, 2);   // N/64, M/64, {prd,arg}
    proj_gemm_mfma<<<g1, 256, 0, stream>>>(seq, w_prd, b_prd, w_arg, b_arg, hp, ha);

    dim3 g2(5, 5, 10);   // a-tiles(32), p-tiles(32), b*c
    scores_kernel<<<g2, 256, 0, stream>>>(hp, ha, w_out, mask, out + 1);

    loss_kernel<<<400, 256, 0, stream>>>(out + 1, targ, acc);
    finalize_kernel<<<1, 1, 0, stream>>>(acc, out);
}

// Round 6
// 113.844 us; speedup vs baseline: 1.0409x; 1.0409x over previous
//
#include <hip/hip_runtime.h>
#include <hip/hip_bf16.h>
#include <math.h>

// B=2, S=160, H=768, C=5 ; M = B*S = 320, N = C*H = 3840, K = H = 768

typedef __attribute__((ext_vector_type(8))) short bf16x8;
typedef __attribute__((ext_vector_type(4))) float f32x4;

__device__ __forceinline__ unsigned short f2bf(float f) {
    union { float f; unsigned u; } v; v.f = f;
    unsigned r = (v.u + 0x7FFFu + ((v.u >> 16) & 1u)) >> 16;
    return (unsigned short)r;
}

// 64x64 output tile per block, BK=32, 4 waves each computing a 32x32 quadrant
// via v_mfma_f32_16x16x32_bf16. Epilogue stores tanh(acc+bias), clamped to
// +-0.999999 so the downstream tanh-addition identity is NaN-safe.
__global__ __launch_bounds__(256) void proj_gemm_mfma(
    const float* __restrict__ A,     // [320, 768]
    const float* __restrict__ Wp,    // [768, 3840]
    const float* __restrict__ bp,    // [3840]
    const float* __restrict__ Wa,
    const float* __restrict__ ba,
    float* __restrict__ hp,          // [320, 3840]  (tanh of projection)
    float* __restrict__ ha)
{
    const int which = blockIdx.z;
    const float* W    = which ? Wa : Wp;
    const float* bias = which ? ba : bp;
    float* out        = which ? ha : hp;

    const int n0 = blockIdx.x * 64;
    const int m0 = blockIdx.y * 64;
    const int tid  = threadIdx.x;
    const int lane = tid & 63;
    const int w    = tid >> 6;

    __shared__ __attribute__((aligned(16))) short As[64][40]; // [m][k], pad 32->40
    __shared__ __attribute__((aligned(16))) short Bs[64][40]; // [n][k] (W transposed)

    f32x4 acc[2][2] = {};

    // staging indices
    const int ra = tid >> 2;          // 0..63 : A row
    const int ka = (tid & 3) * 8;     // 0,8,16,24 : A k-offset
    const int nb = tid & 63;          // 0..63 : B col (n), lane-contiguous
    const int kb = (tid >> 6) * 8;    // 0,8,16,24 : B k-offset

    // fragment indices
    const int wm = (w & 1) * 32;
    const int wn = (w >> 1) * 32;
    const int fr = lane & 15;
    const int fk = (lane >> 4) * 8;

    const float* Arow = A + (size_t)(m0 + ra) * 768 + ka;

    for (int k0 = 0; k0 < 768; k0 += 32) {
        // issue global loads early (in flight across the barrier)
        float4 a0 = *reinterpret_cast<const float4*>(Arow + k0);
        float4 a1 = *reinterpret_cast<const float4*>(Arow + k0 + 4);
        float bvals[8];
        #pragma unroll
        for (int j = 0; j < 8; ++j)
            bvals[j] = W[(size_t)(k0 + kb + j) * 3840 + n0 + nb];

        __syncthreads();  // previous iteration's fragment reads complete

        bf16x8 av;
        av[0] = f2bf(a0.x); av[1] = f2bf(a0.y); av[2] = f2bf(a0.z); av[3] = f2bf(a0.w);
        av[4] = f2bf(a1.x); av[5] = f2bf(a1.y); av[6] = f2bf(a1.z); av[7] = f2bf(a1.w);
        *reinterpret_cast<bf16x8*>(&As[ra][ka]) = av;

        bf16x8 bv;
        #pragma unroll
        for (int j = 0; j < 8; ++j) bv[j] = f2bf(bvals[j]);
        *reinterpret_cast<bf16x8*>(&Bs[nb][kb]) = bv;

        __syncthreads();

        bf16x8 af0 = *reinterpret_cast<const bf16x8*>(&As[wm + fr][fk]);
        bf16x8 af1 = *reinterpret_cast<const bf16x8*>(&As[wm + 16 + fr][fk]);
        bf16x8 bf0 = *reinterpret_cast<const bf16x8*>(&Bs[wn + fr][fk]);
        bf16x8 bf1 = *reinterpret_cast<const bf16x8*>(&Bs[wn + 16 + fr][fk]);

        acc[0][0] = __builtin_amdgcn_mfma_f32_16x16x32_bf16(af0, bf0, acc[0][0], 0, 0, 0);
        acc[0][1] = __builtin_amdgcn_mfma_f32_16x16x32_bf16(af0, bf1, acc[0][1], 0, 0, 0);
        acc[1][0] = __builtin_amdgcn_mfma_f32_16x16x32_bf16(af1, bf0, acc[1][0], 0, 0, 0);
        acc[1][1] = __builtin_amdgcn_mfma_f32_16x16x32_bf16(af1, bf1, acc[1][1], 0, 0, 0);
    }

    // C/D layout: col = lane&15, row = (lane>>4)*4 + reg
    #pragma unroll
    for (int j = 0; j < 2; ++j) {
        const int col = n0 + wn + j * 16 + fr;
        const float bb = bias[col];
        #pragma unroll
        for (int i = 0; i < 2; ++i) {
            #pragma unroll
            for (int r = 0; r < 4; ++r) {
                const int row = m0 + wm + i * 16 + (lane >> 4) * 4 + r;
                float t = tanhf(acc[i][j][r] + bb);
                t = __builtin_amdgcn_fmed3f(t, -0.999999f, 0.999999f);
                out[(size_t)row * 3840 + col] = t;
            }
        }
    }
}

// Pre-fill scores with the mask bias; scores_partial atomically adds partials.
// Also zeroes the loss accumulator (absorbs the old memset dispatch).
__global__ __launch_bounds__(256) void init_scores(
    const int* __restrict__ mask,
    float* __restrict__ sout,        // [256000]
    float* __restrict__ acc)
{
    const int i = blockIdx.x * 256 + threadIdx.x;
    sout[i] = mask[i] ? 0.f : -1024.f;
    if (i < 2) acc[i] = 0.f;
}

// score[b,p,c,a] += sum_{h in half} ((tp+ta)/(1+tp*ta))*w   (exact tanh identity)
// 32x32 (p,a) tile per block, 2x2 outputs per thread, K split in half across z.
__global__ __launch_bounds__(256) void scores_partial(
    const float* __restrict__ tp_g,  // [320, 3840]  tanh(hp)
    const float* __restrict__ ta_g,  // [320, 3840]  tanh(ha)
    const float* __restrict__ w_out, // [768]
    float* __restrict__ out)         // [B,S,C,S], pre-filled with mask bias
{
    const int at0 = blockIdx.x * 32; // 5 tiles
    const int pt0 = blockIdx.y * 32; // 5 tiles
    const int z   = blockIdx.z;      // 0..19
    const int bc  = z >> 1;
    const int kh  = z & 1;           // k half
    const int b = bc / 5, c = bc % 5;

    const int tid = threadIdx.x;
    const int tx = tid & 15;         // a index
    const int ty = tid >> 4;         // p index

    __shared__ __attribute__((aligned(16))) float w_s[384];
    __shared__ __attribute__((aligned(16))) float hp_s[32][132]; // 128 + 4 pad
    __shared__ __attribute__((aligned(16))) float ha_s[32][132];

    if (tid < 96) {
        *reinterpret_cast<float4*>(&w_s[tid * 4]) =
            *reinterpret_cast<const float4*>(&w_out[kh * 384 + tid * 4]);
    }

    const float* hp_base = tp_g + (size_t)(b * 160 + pt0) * 3840 + c * 768 + kh * 384;
    const float* ha_base = ta_g + (size_t)(b * 160 + at0) * 3840 + c * 768 + kh * 384;

    float acc00 = 0.f, acc01 = 0.f, acc10 = 0.f, acc11 = 0.f;

    for (int kc = 0; kc < 384; kc += 128) {
        __syncthreads();   // protects w_s (iter 0) and hp_s/ha_s reuse
        #pragma unroll
        for (int i = 0; i < 4; ++i) {
            int f4  = i * 256 + tid;       // 0..1023
            int row = f4 >> 5;             // 32 rows, 32 float4 each
            int col = (f4 & 31) * 4;
            *reinterpret_cast<float4*>(&hp_s[row][col]) =
                *reinterpret_cast<const float4*>(&hp_base[(size_t)row * 3840 + kc + col]);
            *reinterpret_cast<float4*>(&ha_s[row][col]) =
                *reinterpret_cast<const float4*>(&ha_base[(size_t)row * 3840 + kc + col]);
        }
        __syncthreads();
        #pragma unroll 4
        for (int j = 0; j < 32; ++j) {
            float4 w4 = *reinterpret_cast<const float4*>(&w_s[kc + j * 4]);
            float4 p0 = *reinterpret_cast<const float4*>(&hp_s[ty     ][j * 4]);
            float4 p1 = *reinterpret_cast<const float4*>(&hp_s[ty + 16][j * 4]);
            float4 a0 = *reinterpret_cast<const float4*>(&ha_s[tx     ][j * 4]);
            float4 a1 = *reinterpret_cast<const float4*>(&ha_s[tx + 16][j * 4]);

#define TERM(ACC, P, A, W) \
            { float s_ = (P) + (A); \
              float d_ = fmaf((P), (A), 1.f); \
              ACC = fmaf(s_ * __builtin_amdgcn_rcpf(d_), (W), ACC); }
#define LANE(PX, AX, W) \
            TERM(acc00, p0.PX, a0.AX, W) \
            TERM(acc01, p0.PX, a1.AX, W) \
            TERM(acc10, p1.PX, a0.AX, W) \
            TERM(acc11, p1.PX, a1.AX, W)

            LANE(x, x, w4.x)
            LANE(y, y, w4.y)
            LANE(z, z, w4.z)
            LANE(w, w, w4.w)
#undef LANE
#undef TERM
        }
    }

    #pragma unroll
    for (int pi = 0; pi < 2; ++pi) {
        #pragma unroll
        for (int ai = 0; ai < 2; ++ai) {
            const int p = pt0 + pi * 16 + ty;
            const int a = at0 + ai * 16 + tx;
            const size_t idx = ((size_t)(b * 160 + p) * 5 + c) * 160 + a;
            float v = pi ? (ai ? acc11 : acc10) : (ai ? acc01 : acc00);
            atomicAdd(&out[idx], v);
        }
    }
}

// one wave per (b,p,c) row of 160 args
__global__ __launch_bounds__(256) void loss_kernel(
    const float* __restrict__ scores,  // [1600,160]
    const int*  __restrict__ target,
    float* __restrict__ acc)           // acc[0]=sum(-logsm*t), acc[1]=sum(t)
{
    const int lane = threadIdx.x & 63;
    const int wid  = threadIdx.x >> 6;
    const int row  = blockIdx.x * 4 + wid;  // 0..1599
    const float* x = scores + (size_t)row * 160;
    const int*  t  = target + (size_t)row * 160;

    float x0 = x[lane];
    float x1 = x[lane + 64];
    float x2 = (lane < 32) ? x[lane + 128] : -INFINITY;

    float m = fmaxf(fmaxf(x0, x1), x2);
    #pragma unroll
    for (int o = 32; o >= 1; o >>= 1)
        m = fmaxf(m, __shfl_xor(m, o));

    float s = __expf(x0 - m) + __expf(x1 - m) + ((lane < 32) ? __expf(x2 - m) : 0.f);
    #pragma unroll
    for (int o = 32; o >= 1; o >>= 1)
        s += __shfl_xor(s, o);
    float lse = logf(s) + m;

    int t0 = t[lane], t1 = t[lane + 64];
    int t2 = (lane < 32) ? t[lane + 128] : 0;
    float pl = (float)t0 * (lse - x0) + (float)t1 * (lse - x1)
             + ((lane < 32 && t2) ? (float)t2 * (lse - x2) : 0.f);
    float pts = (float)(t0 + t1 + t2);
    #pragma unroll
    for (int o = 32; o >= 1; o >>= 1) {
        pl  += __shfl_xor(pl, o);
        pts += __shfl_xor(pts, o);
    }
    if (lane == 0) {
        atomicAdd(&acc[0], pl);
        atomicAdd(&acc[1], pts);
    }
}

__global__ void finalize_kernel(const float* __restrict__ acc, float* __restrict__ out0)
{
    out0[0] = acc[0] / (acc[1] + 1e-6f);
}

extern "C" void kernel_launch(void* const* d_in, const int* in_sizes, int n_in,
                              void* d_out, int out_size, void* d_ws, size_t ws_size,
                              hipStream_t stream) {
    const float* seq   = (const float*)d_in[0];
    const float* w_prd = (const float*)d_in[1];
    const float* b_prd = (const float*)d_in[2];
    const float* w_arg = (const float*)d_in[3];
    const float* b_arg = (const float*)d_in[4];
    const float* w_out = (const float*)d_in[5];
    const int*   mask  = (const int*)d_in[6];
    const int*   targ  = (const int*)d_in[7];

    float* out = (float*)d_out;          // out[0]=loss, out+1 = scores [2,160,5,160]
    float* hp  = (float*)d_ws;           // [320,3840]  tanh(h_p)
    float* ha  = hp + 320 * 3840;        // [320,3840]  tanh(h_a)
    float* acc = ha + 320 * 3840;        // [2]

    init_scores<<<1000, 256, 0, stream>>>(mask, out + 1, acc);

    dim3 g1(60, 5, 2);   // N/64, M/64, {prd,arg}
    proj_gemm_mfma<<<g1, 256, 0, stream>>>(seq, w_prd, b_prd, w_arg, b_arg, hp, ha);

    dim3 g2(5, 5, 20);   // a-tiles(32), p-tiles(32), b*c*khalf
    scores_partial<<<g2, 256, 0, stream>>>(hp, ha, w_out, out + 1);

    loss_kernel<<<400, 256, 0, stream>>>(out + 1, targ, acc);
    finalize_kernel<<<1, 1, 0, stream>>>(acc, out);
}

// Round 7
// 110.426 us; speedup vs baseline: 1.0732x; 1.0310x over previous
//
#include <hip/hip_runtime.h>
#include <hip/hip_bf16.h>
#include <math.h>

// B=2, S=160, H=768, C=5 ; M = B*S = 320, N = C*H = 3840, K = H = 768

typedef __attribute__((ext_vector_type(8))) short bf16x8;
typedef __attribute__((ext_vector_type(4))) float f32x4;

__device__ __forceinline__ unsigned short f2bf(float f) {
    union { float f; unsigned u; } v; v.f = f;
    unsigned r = (v.u + 0x7FFFu + ((v.u >> 16) & 1u)) >> 16;
    return (unsigned short)r;
}

// 64x64 output tile per block, BK=32, 4 waves each computing a 32x32 quadrant
// via v_mfma_f32_16x16x32_bf16. Epilogue stores tanh(acc+bias), clamped to
// +-0.999999 so the downstream tanh-addition identity is NaN-safe.
__global__ __launch_bounds__(256) void proj_gemm_mfma(
    const float* __restrict__ A,     // [320, 768]
    const float* __restrict__ Wp,    // [768, 3840]
    const float* __restrict__ bp,    // [3840]
    const float* __restrict__ Wa,
    const float* __restrict__ ba,
    float* __restrict__ hp,          // [320, 3840]  (tanh of projection)
    float* __restrict__ ha)
{
    const int which = blockIdx.z;
    const float* W    = which ? Wa : Wp;
    const float* bias = which ? ba : bp;
    float* out        = which ? ha : hp;

    const int n0 = blockIdx.x * 64;
    const int m0 = blockIdx.y * 64;
    const int tid  = threadIdx.x;
    const int lane = tid & 63;
    const int w    = tid >> 6;

    __shared__ __attribute__((aligned(16))) short As[64][40]; // [m][k], pad 32->40
    __shared__ __attribute__((aligned(16))) short Bs[64][40]; // [n][k] (W transposed)

    f32x4 acc[2][2] = {};

    // staging indices
    const int ra = tid >> 2;          // 0..63 : A row
    const int ka = (tid & 3) * 8;     // 0,8,16,24 : A k-offset
    const int nb = tid & 63;          // 0..63 : B col (n), lane-contiguous
    const int kb = (tid >> 6) * 8;    // 0,8,16,24 : B k-offset

    // fragment indices
    const int wm = (w & 1) * 32;
    const int wn = (w >> 1) * 32;
    const int fr = lane & 15;
    const int fk = (lane >> 4) * 8;

    const float* Arow = A + (size_t)(m0 + ra) * 768 + ka;

    for (int k0 = 0; k0 < 768; k0 += 32) {
        // issue global loads early (in flight across the barrier)
        float4 a0 = *reinterpret_cast<const float4*>(Arow + k0);
        float4 a1 = *reinterpret_cast<const float4*>(Arow + k0 + 4);
        float bvals[8];
        #pragma unroll
        for (int j = 0; j < 8; ++j)
            bvals[j] = W[(size_t)(k0 + kb + j) * 3840 + n0 + nb];

        __syncthreads();  // previous iteration's fragment reads complete

        bf16x8 av;
        av[0] = f2bf(a0.x); av[1] = f2bf(a0.y); av[2] = f2bf(a0.z); av[3] = f2bf(a0.w);
        av[4] = f2bf(a1.x); av[5] = f2bf(a1.y); av[6] = f2bf(a1.z); av[7] = f2bf(a1.w);
        *reinterpret_cast<bf16x8*>(&As[ra][ka]) = av;

        bf16x8 bv;
        #pragma unroll
        for (int j = 0; j < 8; ++j) bv[j] = f2bf(bvals[j]);
        *reinterpret_cast<bf16x8*>(&Bs[nb][kb]) = bv;

        __syncthreads();

        bf16x8 af0 = *reinterpret_cast<const bf16x8*>(&As[wm + fr][fk]);
        bf16x8 af1 = *reinterpret_cast<const bf16x8*>(&As[wm + 16 + fr][fk]);
        bf16x8 bf0 = *reinterpret_cast<const bf16x8*>(&Bs[wn + fr][fk]);
        bf16x8 bf1 = *reinterpret_cast<const bf16x8*>(&Bs[wn + 16 + fr][fk]);

        acc[0][0] = __builtin_amdgcn_mfma_f32_16x16x32_bf16(af0, bf0, acc[0][0], 0, 0, 0);
        acc[0][1] = __builtin_amdgcn_mfma_f32_16x16x32_bf16(af0, bf1, acc[0][1], 0, 0, 0);
        acc[1][0] = __builtin_amdgcn_mfma_f32_16x16x32_bf16(af1, bf0, acc[1][0], 0, 0, 0);
        acc[1][1] = __builtin_amdgcn_mfma_f32_16x16x32_bf16(af1, bf1, acc[1][1], 0, 0, 0);
    }

    // C/D layout: col = lane&15, row = (lane>>4)*4 + reg
    #pragma unroll
    for (int j = 0; j < 2; ++j) {
        const int col = n0 + wn + j * 16 + fr;
        const float bb = bias[col];
        #pragma unroll
        for (int i = 0; i < 2; ++i) {
            #pragma unroll
            for (int r = 0; r < 4; ++r) {
                const int row = m0 + wm + i * 16 + (lane >> 4) * 4 + r;
                float t = tanhf(acc[i][j][r] + bb);
                t = __builtin_amdgcn_fmed3f(t, -0.999999f, 0.999999f);
                out[(size_t)row * 3840 + col] = t;
            }
        }
    }
}

// Pre-fill scores with the mask bias; scores_partial atomically adds partials.
// Also zeroes the loss accumulator (absorbs the old memset dispatch).
__global__ __launch_bounds__(256) void init_scores(
    const int* __restrict__ mask,
    float* __restrict__ sout,        // [256000]
    float* __restrict__ acc)
{
    const int i = blockIdx.x * 256 + threadIdx.x;
    sout[i] = mask[i] ? 0.f : -1024.f;
    if (i < 2) acc[i] = 0.f;
}

// score[b,p,c,a] += sum_{h in quarter} ((tp+ta)/(1+tp*ta))*w   (exact tanh identity)
// 32x32 (p,a) tile per block, 2x2 outputs per thread, K split x4 across z.
__global__ __launch_bounds__(256) void scores_partial(
    const float* __restrict__ tp_g,  // [320, 3840]  tanh(hp)
    const float* __restrict__ ta_g,  // [320, 3840]  tanh(ha)
    const float* __restrict__ w_out, // [768]
    float* __restrict__ out)         // [B,S,C,S], pre-filled with mask bias
{
    const int at0 = blockIdx.x * 32; // 5 tiles
    const int pt0 = blockIdx.y * 32; // 5 tiles
    const int z   = blockIdx.z;      // 0..39
    const int bc  = z >> 2;
    const int kq  = z & 3;           // k quarter (192 floats)
    const int b = bc / 5, c = bc % 5;

    const int tid = threadIdx.x;
    const int tx = tid & 15;         // a index
    const int ty = tid >> 4;         // p index

    __shared__ __attribute__((aligned(16))) float w_s[192];
    __shared__ __attribute__((aligned(16))) float hp_s[32][100]; // 96 + 4 pad
    __shared__ __attribute__((aligned(16))) float ha_s[32][100];

    if (tid < 48) {
        *reinterpret_cast<float4*>(&w_s[tid * 4]) =
            *reinterpret_cast<const float4*>(&w_out[kq * 192 + tid * 4]);
    }

    const float* hp_base = tp_g + (size_t)(b * 160 + pt0) * 3840 + c * 768 + kq * 192;
    const float* ha_base = ta_g + (size_t)(b * 160 + at0) * 3840 + c * 768 + kq * 192;

    float acc00 = 0.f, acc01 = 0.f, acc10 = 0.f, acc11 = 0.f;

    for (int kc = 0; kc < 192; kc += 96) {
        __syncthreads();   // protects w_s (iter 0) and hp_s/ha_s reuse
        #pragma unroll
        for (int i = 0; i < 3; ++i) {
            int f4  = i * 256 + tid;       // 0..767 ; 32 rows x 24 float4
            int row = f4 / 24;
            int col = (f4 % 24) * 4;
            *reinterpret_cast<float4*>(&hp_s[row][col]) =
                *reinterpret_cast<const float4*>(&hp_base[(size_t)row * 3840 + kc + col]);
            *reinterpret_cast<float4*>(&ha_s[row][col]) =
                *reinterpret_cast<const float4*>(&ha_base[(size_t)row * 3840 + kc + col]);
        }
        __syncthreads();
        #pragma unroll 4
        for (int j = 0; j < 24; ++j) {
            float4 w4 = *reinterpret_cast<const float4*>(&w_s[kc + j * 4]);
            float4 p0 = *reinterpret_cast<const float4*>(&hp_s[ty     ][j * 4]);
            float4 p1 = *reinterpret_cast<const float4*>(&hp_s[ty + 16][j * 4]);
            float4 a0 = *reinterpret_cast<const float4*>(&ha_s[tx     ][j * 4]);
            float4 a1 = *reinterpret_cast<const float4*>(&ha_s[tx + 16][j * 4]);

#define TERM(ACC, P, A, W) \
            { float s_ = (P) + (A); \
              float d_ = fmaf((P), (A), 1.f); \
              ACC = fmaf(s_ * __builtin_amdgcn_rcpf(d_), (W), ACC); }
#define LANE(PX, AX, W) \
            TERM(acc00, p0.PX, a0.AX, W) \
            TERM(acc01, p0.PX, a1.AX, W) \
            TERM(acc10, p1.PX, a0.AX, W) \
            TERM(acc11, p1.PX, a1.AX, W)

            LANE(x, x, w4.x)
            LANE(y, y, w4.y)
            LANE(z, z, w4.z)
            LANE(w, w, w4.w)
#undef LANE
#undef TERM
        }
    }

    #pragma unroll
    for (int pi = 0; pi < 2; ++pi) {
        #pragma unroll
        for (int ai = 0; ai < 2; ++ai) {
            const int p = pt0 + pi * 16 + ty;
            const int a = at0 + ai * 16 + tx;
            const size_t idx = ((size_t)(b * 160 + p) * 5 + c) * 160 + a;
            float v = pi ? (ai ? acc11 : acc10) : (ai ? acc01 : acc00);
            atomicAdd(&out[idx], v);
        }
    }
}

// one wave per (b,p,c) row of 160 args
__global__ __launch_bounds__(256) void loss_kernel(
    const float* __restrict__ scores,  // [1600,160]
    const int*  __restrict__ target,
    float* __restrict__ acc)           // acc[0]=sum(-logsm*t), acc[1]=sum(t)
{
    const int lane = threadIdx.x & 63;
    const int wid  = threadIdx.x >> 6;
    const int row  = blockIdx.x * 4 + wid;  // 0..1599
    const float* x = scores + (size_t)row * 160;
    const int*  t  = target + (size_t)row * 160;

    float x0 = x[lane];
    float x1 = x[lane + 64];
    float x2 = (lane < 32) ? x[lane + 128] : -INFINITY;

    float m = fmaxf(fmaxf(x0, x1), x2);
    #pragma unroll
    for (int o = 32; o >= 1; o >>= 1)
        m = fmaxf(m, __shfl_xor(m, o));

    float s = __expf(x0 - m) + __expf(x1 - m) + ((lane < 32) ? __expf(x2 - m) : 0.f);
    #pragma unroll
    for (int o = 32; o >= 1; o >>= 1)
        s += __shfl_xor(s, o);
    float lse = logf(s) + m;

    int t0 = t[lane], t1 = t[lane + 64];
    int t2 = (lane < 32) ? t[lane + 128] : 0;
    float pl = (float)t0 * (lse - x0) + (float)t1 * (lse - x1)
             + ((lane < 32 && t2) ? (float)t2 * (lse - x2) : 0.f);
    float pts = (float)(t0 + t1 + t2);
    #pragma unroll
    for (int o = 32; o >= 1; o >>= 1) {
        pl  += __shfl_xor(pl, o);
        pts += __shfl_xor(pts, o);
    }
    if (lane == 0) {
        atomicAdd(&acc[0], pl);
        atomicAdd(&acc[1], pts);
    }
}

__global__ void finalize_kernel(const float* __restrict__ acc, float* __restrict__ out0)
{
    out0[0] = acc[0] / (acc[1] + 1e-6f);
}

extern "C" void kernel_launch(void* const* d_in, const int* in_sizes, int n_in,
                              void* d_out, int out_size, void* d_ws, size_t ws_size,
                              hipStream_t stream) {
    const float* seq   = (const float*)d_in[0];
    const float* w_prd = (const float*)d_in[1];
    const float* b_prd = (const float*)d_in[2];
    const float* w_arg = (const float*)d_in[3];
    const float* b_arg = (const float*)d_in[4];
    const float* w_out = (const float*)d_in[5];
    const int*   mask  = (const int*)d_in[6];
    const int*   targ  = (const int*)d_in[7];

    float* out = (float*)d_out;          // out[0]=loss, out+1 = scores [2,160,5,160]
    float* hp  = (float*)d_ws;           // [320,3840]  tanh(h_p)
    float* ha  = hp + 320 * 3840;        // [320,3840]  tanh(h_a)
    float* acc = ha + 320 * 3840;        // [2]

    init_scores<<<1000, 256, 0, stream>>>(mask, out + 1, acc);

    dim3 g1(60, 5, 2);   // N/64, M/64, {prd,arg}
    proj_gemm_mfma<<<g1, 256, 0, stream>>>(seq, w_prd, b_prd, w_arg, b_arg, hp, ha);

    dim3 g2(5, 5, 40);   // a-tiles(32), p-tiles(32), b*c*kquarter
    scores_partial<<<g2, 256, 0, stream>>>(hp, ha, w_out, out + 1);

    loss_kernel<<<400, 256, 0, stream>>>(out + 1, targ, acc);
    finalize_kernel<<<1, 1, 0, stream>>>(acc, out);
}

// Round 8
// 109.789 us; speedup vs baseline: 1.0794x; 1.0058x over previous
//
#include <hip/hip_runtime.h>
#include <hip/hip_bf16.h>
#include <math.h>

// B=2, S=160, H=768, C=5 ; M = B*S = 320, N = C*H = 3840, K = H = 768

typedef __attribute__((ext_vector_type(8))) short bf16x8;
typedef __attribute__((ext_vector_type(4))) float f32x4;

__device__ __forceinline__ unsigned short f2bf(float f) {
    union { float f; unsigned u; } v; v.f = f;
    unsigned r = (v.u + 0x7FFFu + ((v.u >> 16) & 1u)) >> 16;
    return (unsigned short)r;
}

// fp32 -> bf16 for A (320x768), Wp, Wa (768x3840 each). 8 elems/thread, exact grid.
__global__ __launch_bounds__(256) void convert_bf16(
    const float* __restrict__ A,
    const float* __restrict__ Wp,
    const float* __restrict__ Wa,
    unsigned short* __restrict__ A_bf,
    unsigned short* __restrict__ Wp_bf,
    unsigned short* __restrict__ Wa_bf)
{
    const int NA = 320 * 768 / 8;      // 30720 groups
    const int NW = 768 * 3840 / 8;     // 368640 groups
    int i = blockIdx.x * 256 + threadIdx.x;   // < NA + 2*NW = 768000
    const float* src; unsigned short* dst; int off;
    if (i < NA)            { src = A;  dst = A_bf;  off = i; }
    else if (i < NA + NW)  { src = Wp; dst = Wp_bf; off = i - NA; }
    else                   { src = Wa; dst = Wa_bf; off = i - NA - NW; }
    float4 v0 = *reinterpret_cast<const float4*>(src + (size_t)off * 8);
    float4 v1 = *reinterpret_cast<const float4*>(src + (size_t)off * 8 + 4);
    bf16x8 o;
    o[0] = f2bf(v0.x); o[1] = f2bf(v0.y); o[2] = f2bf(v0.z); o[3] = f2bf(v0.w);
    o[4] = f2bf(v1.x); o[5] = f2bf(v1.y); o[6] = f2bf(v1.z); o[7] = f2bf(v1.w);
    *reinterpret_cast<bf16x8*>(dst + (size_t)off * 8) = o;
}

// 64x64 tile, BK=64, 4 waves x (2x2 fragments x2 k-blocks) of mfma_16x16x32_bf16.
// Inputs pre-converted bf16 -> no VALU conversion in the loop.
// Epilogue stores clamped tanh(acc+bias) for the tanh-addition identity downstream.
__global__ __launch_bounds__(256) void proj_gemm_bf16(
    const unsigned short* __restrict__ A_bf,   // [320][768]
    const unsigned short* __restrict__ Wp_bf,  // [768][3840]
    const float* __restrict__ bp,
    const unsigned short* __restrict__ Wa_bf,
    const float* __restrict__ ba,
    float* __restrict__ hp,                    // [320][3840] tanh(proj)
    float* __restrict__ ha)
{
    const int which = blockIdx.z;
    const unsigned short* W = which ? Wa_bf : Wp_bf;
    const float* bias       = which ? ba : bp;
    float* out              = which ? ha : hp;

    const int n0 = blockIdx.x * 64;
    const int m0 = blockIdx.y * 64;
    const int tid  = threadIdx.x;
    const int lane = tid & 63;
    const int w    = tid >> 6;

    __shared__ __attribute__((aligned(16))) unsigned short As[64][72]; // [m][k] pad
    __shared__ __attribute__((aligned(16))) unsigned short Bs[64][72]; // [n][k] pad

    f32x4 acc[2][2] = {};

    // A staging: thread t -> row m=t>>2, k-quarter (t&3)*16 (two b128 in/out)
    const int am = tid >> 2;
    const int ak = (tid & 3) * 16;
    const unsigned short* Arow = A_bf + (size_t)(m0 + am) * 768 + ak;

    // B staging: thread t -> col n=t&63, k-seg (t>>6)*16 (16 coalesced scalar loads)
    const int nb = tid & 63;
    const int kt = (tid >> 6) * 16;
    const unsigned short* Wbase = W + (size_t)kt * 3840 + n0 + nb;

    // fragment indices
    const int wm = (w & 1) * 32;
    const int wn = (w >> 1) * 32;
    const int fr = lane & 15;
    const int fk = (lane >> 4) * 8;

    for (int k0 = 0; k0 < 768; k0 += 64) {
        // global loads first (overlap with prev MFMAs; no LDS touched yet)
        bf16x8 a0 = *reinterpret_cast<const bf16x8*>(Arow + k0);
        bf16x8 a1 = *reinterpret_cast<const bf16x8*>(Arow + k0 + 8);
        unsigned short bv[16];
        const unsigned short* wp = Wbase + (size_t)k0 * 3840;
        #pragma unroll
        for (int j = 0; j < 16; ++j) bv[j] = wp[(size_t)j * 3840];

        __syncthreads();   // previous iteration's fragment reads complete

        *reinterpret_cast<bf16x8*>(&As[am][ak])     = a0;
        *reinterpret_cast<bf16x8*>(&As[am][ak + 8]) = a1;
        bf16x8 b0, b1;
        #pragma unroll
        for (int j = 0; j < 8; ++j) { b0[j] = (short)bv[j]; b1[j] = (short)bv[8 + j]; }
        *reinterpret_cast<bf16x8*>(&Bs[nb][kt])     = b0;
        *reinterpret_cast<bf16x8*>(&Bs[nb][kt + 8]) = b1;

        __syncthreads();

        #pragma unroll
        for (int kk = 0; kk < 2; ++kk) {
            const int kc = kk * 32 + fk;
            bf16x8 af0 = *reinterpret_cast<const bf16x8*>(&As[wm + fr][kc]);
            bf16x8 af1 = *reinterpret_cast<const bf16x8*>(&As[wm + 16 + fr][kc]);
            bf16x8 bg0 = *reinterpret_cast<const bf16x8*>(&Bs[wn + fr][kc]);
            bf16x8 bg1 = *reinterpret_cast<const bf16x8*>(&Bs[wn + 16 + fr][kc]);
            acc[0][0] = __builtin_amdgcn_mfma_f32_16x16x32_bf16(af0, bg0, acc[0][0], 0, 0, 0);
            acc[0][1] = __builtin_amdgcn_mfma_f32_16x16x32_bf16(af0, bg1, acc[0][1], 0, 0, 0);
            acc[1][0] = __builtin_amdgcn_mfma_f32_16x16x32_bf16(af1, bg0, acc[1][0], 0, 0, 0);
            acc[1][1] = __builtin_amdgcn_mfma_f32_16x16x32_bf16(af1, bg1, acc[1][1], 0, 0, 0);
        }
    }

    // C/D layout: col = lane&15, row = (lane>>4)*4 + reg
    #pragma unroll
    for (int j = 0; j < 2; ++j) {
        const int col = n0 + wn + j * 16 + fr;
        const float bb = bias[col];
        #pragma unroll
        for (int i = 0; i < 2; ++i) {
            #pragma unroll
            for (int r = 0; r < 4; ++r) {
                const int row = m0 + wm + i * 16 + (lane >> 4) * 4 + r;
                float t = tanhf(acc[i][j][r] + bb);
                t = __builtin_amdgcn_fmed3f(t, -0.999999f, 0.999999f);
                out[(size_t)row * 3840 + col] = t;
            }
        }
    }
}

// Pre-fill scores with the mask bias; scores_partial atomically adds partials.
__global__ __launch_bounds__(256) void init_scores(
    const int* __restrict__ mask,
    float* __restrict__ sout,        // [256000]
    float* __restrict__ acc)
{
    const int i = blockIdx.x * 256 + threadIdx.x;
    sout[i] = mask[i] ? 0.f : -1024.f;
    if (i < 2) acc[i] = 0.f;
}

// score[b,p,c,a] += sum_{h in quarter} ((tp+ta)/(1+tp*ta))*w   (exact tanh identity)
__global__ __launch_bounds__(256) void scores_partial(
    const float* __restrict__ tp_g,  // [320, 3840]  tanh(hp)
    const float* __restrict__ ta_g,  // [320, 3840]  tanh(ha)
    const float* __restrict__ w_out, // [768]
    float* __restrict__ out)         // [B,S,C,S], pre-filled with mask bias
{
    const int at0 = blockIdx.x * 32;
    const int pt0 = blockIdx.y * 32;
    const int z   = blockIdx.z;      // 0..39
    const int bc  = z >> 2;
    const int kq  = z & 3;           // k quarter (192 floats)
    const int b = bc / 5, c = bc % 5;

    const int tid = threadIdx.x;
    const int tx = tid & 15;
    const int ty = tid >> 4;

    __shared__ __attribute__((aligned(16))) float w_s[192];
    __shared__ __attribute__((aligned(16))) float hp_s[32][100];
    __shared__ __attribute__((aligned(16))) float ha_s[32][100];

    if (tid < 48) {
        *reinterpret_cast<float4*>(&w_s[tid * 4]) =
            *reinterpret_cast<const float4*>(&w_out[kq * 192 + tid * 4]);
    }

    const float* hp_base = tp_g + (size_t)(b * 160 + pt0) * 3840 + c * 768 + kq * 192;
    const float* ha_base = ta_g + (size_t)(b * 160 + at0) * 3840 + c * 768 + kq * 192;

    float acc00 = 0.f, acc01 = 0.f, acc10 = 0.f, acc11 = 0.f;

    for (int kc = 0; kc < 192; kc += 96) {
        __syncthreads();
        #pragma unroll
        for (int i = 0; i < 3; ++i) {
            int f4  = i * 256 + tid;       // 0..767 ; 32 rows x 24 float4
            int row = f4 / 24;
            int col = (f4 % 24) * 4;
            *reinterpret_cast<float4*>(&hp_s[row][col]) =
                *reinterpret_cast<const float4*>(&hp_base[(size_t)row * 3840 + kc + col]);
            *reinterpret_cast<float4*>(&ha_s[row][col]) =
                *reinterpret_cast<const float4*>(&ha_base[(size_t)row * 3840 + kc + col]);
        }
        __syncthreads();
        #pragma unroll 4
        for (int j = 0; j < 24; ++j) {
            float4 w4 = *reinterpret_cast<const float4*>(&w_s[kc + j * 4]);
            float4 p0 = *reinterpret_cast<const float4*>(&hp_s[ty     ][j * 4]);
            float4 p1 = *reinterpret_cast<const float4*>(&hp_s[ty + 16][j * 4]);
            float4 a0 = *reinterpret_cast<const float4*>(&ha_s[tx     ][j * 4]);
            float4 a1 = *reinterpret_cast<const float4*>(&ha_s[tx + 16][j * 4]);

#define TERM(ACC, P, A, W) \
            { float s_ = (P) + (A); \
              float d_ = fmaf((P), (A), 1.f); \
              ACC = fmaf(s_ * __builtin_amdgcn_rcpf(d_), (W), ACC); }
#define LANE(PX, AX, W) \
            TERM(acc00, p0.PX, a0.AX, W) \
            TERM(acc01, p0.PX, a1.AX, W) \
            TERM(acc10, p1.PX, a0.AX, W) \
            TERM(acc11, p1.PX, a1.AX, W)

            LANE(x, x, w4.x)
            LANE(y, y, w4.y)
            LANE(z, z, w4.z)
            LANE(w, w, w4.w)
#undef LANE
#undef TERM
        }
    }

    #pragma unroll
    for (int pi = 0; pi < 2; ++pi) {
        #pragma unroll
        for (int ai = 0; ai < 2; ++ai) {
            const int p = pt0 + pi * 16 + ty;
            const int a = at0 + ai * 16 + tx;
            const size_t idx = ((size_t)(b * 160 + p) * 5 + c) * 160 + a;
            float v = pi ? (ai ? acc11 : acc10) : (ai ? acc01 : acc00);
            atomicAdd(&out[idx], v);
        }
    }
}

// one wave per (b,p,c) row of 160 args
__global__ __launch_bounds__(256) void loss_kernel(
    const float* __restrict__ scores,  // [1600,160]
    const int*  __restrict__ target,
    float* __restrict__ acc)           // acc[0]=sum(-logsm*t), acc[1]=sum(t)
{
    const int lane = threadIdx.x & 63;
    const int wid  = threadIdx.x >> 6;
    const int row  = blockIdx.x * 4 + wid;  // 0..1599
    const float* x = scores + (size_t)row * 160;
    const int*  t  = target + (size_t)row * 160;

    float x0 = x[lane];
    float x1 = x[lane + 64];
    float x2 = (lane < 32) ? x[lane + 128] : -INFINITY;

    float m = fmaxf(fmaxf(x0, x1), x2);
    #pragma unroll
    for (int o = 32; o >= 1; o >>= 1)
        m = fmaxf(m, __shfl_xor(m, o));

    float s = __expf(x0 - m) + __expf(x1 - m) + ((lane < 32) ? __expf(x2 - m) : 0.f);
    #pragma unroll
    for (int o = 32; o >= 1; o >>= 1)
        s += __shfl_xor(s, o);
    float lse = logf(s) + m;

    int t0 = t[lane], t1 = t[lane + 64];
    int t2 = (lane < 32) ? t[lane + 128] : 0;
    float pl = (float)t0 * (lse - x0) + (float)t1 * (lse - x1)
             + ((lane < 32 && t2) ? (float)t2 * (lse - x2) : 0.f);
    float pts = (float)(t0 + t1 + t2);
    #pragma unroll
    for (int o = 32; o >= 1; o >>= 1) {
        pl  += __shfl_xor(pl, o);
        pts += __shfl_xor(pts, o);
    }
    if (lane == 0) {
        atomicAdd(&acc[0], pl);
        atomicAdd(&acc[1], pts);
    }
}

__global__ void finalize_kernel(const float* __restrict__ acc, float* __restrict__ out0)
{
    out0[0] = acc[0] / (acc[1] + 1e-6f);
}

extern "C" void kernel_launch(void* const* d_in, const int* in_sizes, int n_in,
                              void* d_out, int out_size, void* d_ws, size_t ws_size,
                              hipStream_t stream) {
    const float* seq   = (const float*)d_in[0];
    const float* w_prd = (const float*)d_in[1];
    const float* b_prd = (const float*)d_in[2];
    const float* w_arg = (const float*)d_in[3];
    const float* b_arg = (const float*)d_in[4];
    const float* w_out = (const float*)d_in[5];
    const int*   mask  = (const int*)d_in[6];
    const int*   targ  = (const int*)d_in[7];

    float* out = (float*)d_out;          // out[0]=loss, out+1 = scores [2,160,5,160]

    char* ws = (char*)d_ws;
    float* hp  = (float*)ws;                         // 320*3840 f32
    float* ha  = (float*)(ws + 4915200);             // 320*3840 f32
    float* acc = (float*)(ws + 9830400);             // 2 f32
    unsigned short* A_bf  = (unsigned short*)(ws + 9830416);   // 320*768
    unsigned short* Wp_bf = (unsigned short*)(ws + 10321936);  // 768*3840
    unsigned short* Wa_bf = (unsigned short*)(ws + 16220176);  // 768*3840

    convert_bf16<<<3000, 256, 0, stream>>>(seq, w_prd, w_arg, A_bf, Wp_bf, Wa_bf);

    init_scores<<<1000, 256, 0, stream>>>(mask, out + 1, acc);

    dim3 g1(60, 5, 2);   // N/64, M/64, {prd,arg}
    proj_gemm_bf16<<<g1, 256, 0, stream>>>(A_bf, Wp_bf, b_prd, Wa_bf, b_arg, hp, ha);

    dim3 g2(5, 5, 40);   // a-tiles(32), p-tiles(32), b*c*kquarter
    scores_partial<<<g2, 256, 0, stream>>>(hp, ha, w_out, out + 1);

    loss_kernel<<<400, 256, 0, stream>>>(out + 1, targ, acc);
    finalize_kernel<<<1, 1, 0, stream>>>(acc, out);
}

// Round 9
// 68.147 us; speedup vs baseline: 1.7390x; 1.6111x over previous
//
#include <hip/hip_runtime.h>
#include <hip/hip_bf16.h>
#include <math.h>

// B=2, S=160, H=768, C=5 ; M = B*S = 320, N = C*H = 3840, K = H = 768

typedef __attribute__((ext_vector_type(8))) short bf16x8;
typedef __attribute__((ext_vector_type(4))) float f32x4;

__device__ __forceinline__ unsigned short f2bf(float f) {
    union { float f; unsigned u; } v; v.f = f;
    unsigned r = (v.u + 0x7FFFu + ((v.u >> 16) & 1u)) >> 16;
    return (unsigned short)r;
}

// fp32 -> bf16 for A (320x768), Wp, Wa (768x3840 each). 8 elems/thread, exact grid.
__global__ __launch_bounds__(256) void convert_bf16(
    const float* __restrict__ A,
    const float* __restrict__ Wp,
    const float* __restrict__ Wa,
    unsigned short* __restrict__ A_bf,
    unsigned short* __restrict__ Wp_bf,
    unsigned short* __restrict__ Wa_bf)
{
    const int NA = 320 * 768 / 8;      // 30720 groups
    const int NW = 768 * 3840 / 8;     // 368640 groups
    int i = blockIdx.x * 256 + threadIdx.x;   // < NA + 2*NW = 768000
    const float* src; unsigned short* dst; int off;
    if (i < NA)            { src = A;  dst = A_bf;  off = i; }
    else if (i < NA + NW)  { src = Wp; dst = Wp_bf; off = i - NA; }
    else                   { src = Wa; dst = Wa_bf; off = i - NA - NW; }
    float4 v0 = *reinterpret_cast<const float4*>(src + (size_t)off * 8);
    float4 v1 = *reinterpret_cast<const float4*>(src + (size_t)off * 8 + 4);
    bf16x8 o;
    o[0] = f2bf(v0.x); o[1] = f2bf(v0.y); o[2] = f2bf(v0.z); o[3] = f2bf(v0.w);
    o[4] = f2bf(v1.x); o[5] = f2bf(v1.y); o[6] = f2bf(v1.z); o[7] = f2bf(v1.w);
    *reinterpret_cast<bf16x8*>(dst + (size_t)off * 8) = o;
}

// 64x64 tile, BK=64, 4 waves x (2x2 fragments x2 k-blocks) of mfma_16x16x32_bf16.
// Epilogue stores clamped tanh(acc+bias) for the tanh-addition identity downstream.
__global__ __launch_bounds__(256) void proj_gemm_bf16(
    const unsigned short* __restrict__ A_bf,   // [320][768]
    const unsigned short* __restrict__ Wp_bf,  // [768][3840]
    const float* __restrict__ bp,
    const unsigned short* __restrict__ Wa_bf,
    const float* __restrict__ ba,
    float* __restrict__ hp,                    // [320][3840] tanh(proj)
    float* __restrict__ ha)
{
    const int which = blockIdx.z;
    const unsigned short* W = which ? Wa_bf : Wp_bf;
    const float* bias       = which ? ba : bp;
    float* out              = which ? ha : hp;

    const int n0 = blockIdx.x * 64;
    const int m0 = blockIdx.y * 64;
    const int tid  = threadIdx.x;
    const int lane = tid & 63;
    const int w    = tid >> 6;

    __shared__ __attribute__((aligned(16))) unsigned short As[64][72]; // [m][k] pad
    __shared__ __attribute__((aligned(16))) unsigned short Bs[64][72]; // [n][k] pad

    f32x4 acc[2][2] = {};

    const int am = tid >> 2;
    const int ak = (tid & 3) * 16;
    const unsigned short* Arow = A_bf + (size_t)(m0 + am) * 768 + ak;

    const int nb = tid & 63;
    const int kt = (tid >> 6) * 16;
    const unsigned short* Wbase = W + (size_t)kt * 3840 + n0 + nb;

    const int wm = (w & 1) * 32;
    const int wn = (w >> 1) * 32;
    const int fr = lane & 15;
    const int fk = (lane >> 4) * 8;

    for (int k0 = 0; k0 < 768; k0 += 64) {
        bf16x8 a0 = *reinterpret_cast<const bf16x8*>(Arow + k0);
        bf16x8 a1 = *reinterpret_cast<const bf16x8*>(Arow + k0 + 8);
        unsigned short bv[16];
        const unsigned short* wp = Wbase + (size_t)k0 * 3840;
        #pragma unroll
        for (int j = 0; j < 16; ++j) bv[j] = wp[(size_t)j * 3840];

        __syncthreads();

        *reinterpret_cast<bf16x8*>(&As[am][ak])     = a0;
        *reinterpret_cast<bf16x8*>(&As[am][ak + 8]) = a1;
        bf16x8 b0, b1;
        #pragma unroll
        for (int j = 0; j < 8; ++j) { b0[j] = (short)bv[j]; b1[j] = (short)bv[8 + j]; }
        *reinterpret_cast<bf16x8*>(&Bs[nb][kt])     = b0;
        *reinterpret_cast<bf16x8*>(&Bs[nb][kt + 8]) = b1;

        __syncthreads();

        #pragma unroll
        for (int kk = 0; kk < 2; ++kk) {
            const int kc = kk * 32 + fk;
            bf16x8 af0 = *reinterpret_cast<const bf16x8*>(&As[wm + fr][kc]);
            bf16x8 af1 = *reinterpret_cast<const bf16x8*>(&As[wm + 16 + fr][kc]);
            bf16x8 bg0 = *reinterpret_cast<const bf16x8*>(&Bs[wn + fr][kc]);
            bf16x8 bg1 = *reinterpret_cast<const bf16x8*>(&Bs[wn + 16 + fr][kc]);
            acc[0][0] = __builtin_amdgcn_mfma_f32_16x16x32_bf16(af0, bg0, acc[0][0], 0, 0, 0);
            acc[0][1] = __builtin_amdgcn_mfma_f32_16x16x32_bf16(af0, bg1, acc[0][1], 0, 0, 0);
            acc[1][0] = __builtin_amdgcn_mfma_f32_16x16x32_bf16(af1, bg0, acc[1][0], 0, 0, 0);
            acc[1][1] = __builtin_amdgcn_mfma_f32_16x16x32_bf16(af1, bg1, acc[1][1], 0, 0, 0);
        }
    }

    // C/D layout: col = lane&15, row = (lane>>4)*4 + reg
    #pragma unroll
    for (int j = 0; j < 2; ++j) {
        const int col = n0 + wn + j * 16 + fr;
        const float bb = bias[col];
        #pragma unroll
        for (int i = 0; i < 2; ++i) {
            #pragma unroll
            for (int r = 0; r < 4; ++r) {
                const int row = m0 + wm + i * 16 + (lane >> 4) * 4 + r;
                float t = tanhf(acc[i][j][r] + bb);
                t = __builtin_amdgcn_fmed3f(t, -0.999999f, 0.999999f);
                out[(size_t)row * 3840 + col] = t;
            }
        }
    }
}

// Pre-fill scores with the mask bias; scores_partial atomically adds partials.
__global__ __launch_bounds__(256) void init_scores(
    const int* __restrict__ mask,
    float* __restrict__ sout)        // [256000]
{
    const int i = blockIdx.x * 256 + threadIdx.x;
    sout[i] = mask[i] ? 0.f : -1024.f;
}

// score[b,p,c,a] += sum_{h in quarter} ((tp+ta)/(1+tp*ta))*w   (exact tanh identity)
__global__ __launch_bounds__(256) void scores_partial(
    const float* __restrict__ tp_g,  // [320, 3840]  tanh(hp)
    const float* __restrict__ ta_g,  // [320, 3840]  tanh(ha)
    const float* __restrict__ w_out, // [768]
    float* __restrict__ out)         // [B,S,C,S], pre-filled with mask bias
{
    const int at0 = blockIdx.x * 32;
    const int pt0 = blockIdx.y * 32;
    const int z   = blockIdx.z;      // 0..39
    const int bc  = z >> 2;
    const int kq  = z & 3;           // k quarter (192 floats)
    const int b = bc / 5, c = bc % 5;

    const int tid = threadIdx.x;
    const int tx = tid & 15;
    const int ty = tid >> 4;

    __shared__ __attribute__((aligned(16))) float w_s[192];
    __shared__ __attribute__((aligned(16))) float hp_s[32][100];
    __shared__ __attribute__((aligned(16))) float ha_s[32][100];

    if (tid < 48) {
        *reinterpret_cast<float4*>(&w_s[tid * 4]) =
            *reinterpret_cast<const float4*>(&w_out[kq * 192 + tid * 4]);
    }

    const float* hp_base = tp_g + (size_t)(b * 160 + pt0) * 3840 + c * 768 + kq * 192;
    const float* ha_base = ta_g + (size_t)(b * 160 + at0) * 3840 + c * 768 + kq * 192;

    float acc00 = 0.f, acc01 = 0.f, acc10 = 0.f, acc11 = 0.f;

    for (int kc = 0; kc < 192; kc += 96) {
        __syncthreads();
        #pragma unroll
        for (int i = 0; i < 3; ++i) {
            int f4  = i * 256 + tid;       // 0..767 ; 32 rows x 24 float4
            int row = f4 / 24;
            int col = (f4 % 24) * 4;
            *reinterpret_cast<float4*>(&hp_s[row][col]) =
                *reinterpret_cast<const float4*>(&hp_base[(size_t)row * 3840 + kc + col]);
            *reinterpret_cast<float4*>(&ha_s[row][col]) =
                *reinterpret_cast<const float4*>(&ha_base[(size_t)row * 3840 + kc + col]);
        }
        __syncthreads();
        #pragma unroll 4
        for (int j = 0; j < 24; ++j) {
            float4 w4 = *reinterpret_cast<const float4*>(&w_s[kc + j * 4]);
            float4 p0 = *reinterpret_cast<const float4*>(&hp_s[ty     ][j * 4]);
            float4 p1 = *reinterpret_cast<const float4*>(&hp_s[ty + 16][j * 4]);
            float4 a0 = *reinterpret_cast<const float4*>(&ha_s[tx     ][j * 4]);
            float4 a1 = *reinterpret_cast<const float4*>(&ha_s[tx + 16][j * 4]);

#define TERM(ACC, P, A, W) \
            { float s_ = (P) + (A); \
              float d_ = fmaf((P), (A), 1.f); \
              ACC = fmaf(s_ * __builtin_amdgcn_rcpf(d_), (W), ACC); }
#define LANE(PX, AX, W) \
            TERM(acc00, p0.PX, a0.AX, W) \
            TERM(acc01, p0.PX, a1.AX, W) \
            TERM(acc10, p1.PX, a0.AX, W) \
            TERM(acc11, p1.PX, a1.AX, W)

            LANE(x, x, w4.x)
            LANE(y, y, w4.y)
            LANE(z, z, w4.z)
            LANE(w, w, w4.w)
#undef LANE
#undef TERM
        }
    }

    #pragma unroll
    for (int pi = 0; pi < 2; ++pi) {
        #pragma unroll
        for (int ai = 0; ai < 2; ++ai) {
            const int p = pt0 + pi * 16 + ty;
            const int a = at0 + ai * 16 + tx;
            const size_t idx = ((size_t)(b * 160 + p) * 5 + c) * 160 + a;
            float v = pi ? (ai ? acc11 : acc10) : (ai ? acc01 : acc00);
            atomicAdd(&out[idx], v);
        }
    }
}

// one wave per (b,p,c) row of 160 args; per-block partial -> part[blk] (NO atomics)
__global__ __launch_bounds__(256) void loss_kernel(
    const float* __restrict__ scores,  // [1600,160]
    const int*  __restrict__ target,
    float* __restrict__ part)          // [400][2]
{
    const int lane = threadIdx.x & 63;
    const int wid  = threadIdx.x >> 6;
    const int row  = blockIdx.x * 4 + wid;  // 0..1599
    const float* x = scores + (size_t)row * 160;
    const int*  t  = target + (size_t)row * 160;

    float x0 = x[lane];
    float x1 = x[lane + 64];
    float x2 = (lane < 32) ? x[lane + 128] : -INFINITY;

    float m = fmaxf(fmaxf(x0, x1), x2);
    #pragma unroll
    for (int o = 32; o >= 1; o >>= 1)
        m = fmaxf(m, __shfl_xor(m, o));

    float s = __expf(x0 - m) + __expf(x1 - m) + ((lane < 32) ? __expf(x2 - m) : 0.f);
    #pragma unroll
    for (int o = 32; o >= 1; o >>= 1)
        s += __shfl_xor(s, o);
    float lse = logf(s) + m;

    int t0 = t[lane], t1 = t[lane + 64];
    int t2 = (lane < 32) ? t[lane + 128] : 0;
    float pl = (float)t0 * (lse - x0) + (float)t1 * (lse - x1)
             + ((lane < 32 && t2) ? (float)t2 * (lse - x2) : 0.f);
    float pts = (float)(t0 + t1 + t2);
    #pragma unroll
    for (int o = 32; o >= 1; o >>= 1) {
        pl  += __shfl_xor(pl, o);
        pts += __shfl_xor(pts, o);
    }

    __shared__ float sp[4], st[4];
    if (lane == 0) { sp[wid] = pl; st[wid] = pts; }
    __syncthreads();
    if (threadIdx.x == 0) {
        part[blockIdx.x * 2]     = sp[0] + sp[1] + sp[2] + sp[3];
        part[blockIdx.x * 2 + 1] = st[0] + st[1] + st[2] + st[3];
    }
}

// single block: reduce 400 (pl, pts) pairs -> loss
__global__ __launch_bounds__(256) void finalize_kernel(
    const float* __restrict__ part, float* __restrict__ out0)
{
    const int tid = threadIdx.x;
    float pl = 0.f, pts = 0.f;
    for (int i = tid; i < 400; i += 256) {
        pl  += part[i * 2];
        pts += part[i * 2 + 1];
    }
    #pragma unroll
    for (int o = 32; o >= 1; o >>= 1) {
        pl  += __shfl_xor(pl, o);
        pts += __shfl_xor(pts, o);
    }
    __shared__ float sp[4], st[4];
    const int wid = tid >> 6;
    if ((tid & 63) == 0) { sp[wid] = pl; st[wid] = pts; }
    __syncthreads();
    if (tid == 0) {
        float tl = sp[0] + sp[1] + sp[2] + sp[3];
        float tt = st[0] + st[1] + st[2] + st[3];
        out0[0] = tl / (tt + 1e-6f);
    }
}

extern "C" void kernel_launch(void* const* d_in, const int* in_sizes, int n_in,
                              void* d_out, int out_size, void* d_ws, size_t ws_size,
                              hipStream_t stream) {
    const float* seq   = (const float*)d_in[0];
    const float* w_prd = (const float*)d_in[1];
    const float* b_prd = (const float*)d_in[2];
    const float* w_arg = (const float*)d_in[3];
    const float* b_arg = (const float*)d_in[4];
    const float* w_out = (const float*)d_in[5];
    const int*   mask  = (const int*)d_in[6];
    const int*   targ  = (const int*)d_in[7];

    float* out = (float*)d_out;          // out[0]=loss, out+1 = scores [2,160,5,160]

    char* ws = (char*)d_ws;
    float* hp   = (float*)ws;                        // 320*3840 f32
    float* ha   = (float*)(ws + 4915200);            // 320*3840 f32
    float* part = (float*)(ws + 9830400);            // 400*2 f32 (3200 B)
    unsigned short* A_bf  = (unsigned short*)(ws + 9833600);   // 320*768
    unsigned short* Wp_bf = (unsigned short*)(ws + 10325120);  // 768*3840
    unsigned short* Wa_bf = (unsigned short*)(ws + 16223360);  // 768*3840

    convert_bf16<<<3000, 256, 0, stream>>>(seq, w_prd, w_arg, A_bf, Wp_bf, Wa_bf);

    init_scores<<<1000, 256, 0, stream>>>(mask, out + 1);

    dim3 g1(60, 5, 2);   // N/64, M/64, {prd,arg}
    proj_gemm_bf16<<<g1, 256, 0, stream>>>(A_bf, Wp_bf, b_prd, Wa_bf, b_arg, hp, ha);

    dim3 g2(5, 5, 40);   // a-tiles(32), p-tiles(32), b*c*kquarter
    scores_partial<<<g2, 256, 0, stream>>>(hp, ha, w_out, out + 1);

    loss_kernel<<<400, 256, 0, stream>>>(out + 1, targ, part);
    finalize_kernel<<<1, 256, 0, stream>>>(part, out);
}

// Round 10
// 67.850 us; speedup vs baseline: 1.7466x; 1.0044x over previous
//
#include <hip/hip_runtime.h>
#include <hip/hip_bf16.h>
#include <math.h>

// B=2, S=160, H=768, C=5 ; M = B*S = 320, N = C*H = 3840, K = H = 768

typedef __attribute__((ext_vector_type(8))) short bf16x8;
typedef __attribute__((ext_vector_type(4))) float f32x4;

__device__ __forceinline__ unsigned short f2bf(float f) {
    union { float f; unsigned u; } v; v.f = f;
    unsigned r = (v.u + 0x7FFFu + ((v.u >> 16) & 1u)) >> 16;
    return (unsigned short)r;
}

// fp32 -> bf16 for A (320x768), Wp, Wa (768x3840 each). 8 elems/thread, exact grid.
__global__ __launch_bounds__(256) void convert_bf16(
    const float* __restrict__ A,
    const float* __restrict__ Wp,
    const float* __restrict__ Wa,
    unsigned short* __restrict__ A_bf,
    unsigned short* __restrict__ Wp_bf,
    unsigned short* __restrict__ Wa_bf)
{
    const int NA = 320 * 768 / 8;      // 30720 groups
    const int NW = 768 * 3840 / 8;     // 368640 groups
    int i = blockIdx.x * 256 + threadIdx.x;   // < NA + 2*NW = 768000
    const float* src; unsigned short* dst; int off;
    if (i < NA)            { src = A;  dst = A_bf;  off = i; }
    else if (i < NA + NW)  { src = Wp; dst = Wp_bf; off = i - NA; }
    else                   { src = Wa; dst = Wa_bf; off = i - NA - NW; }
    float4 v0 = *reinterpret_cast<const float4*>(src + (size_t)off * 8);
    float4 v1 = *reinterpret_cast<const float4*>(src + (size_t)off * 8 + 4);
    bf16x8 o;
    o[0] = f2bf(v0.x); o[1] = f2bf(v0.y); o[2] = f2bf(v0.z); o[3] = f2bf(v0.w);
    o[4] = f2bf(v1.x); o[5] = f2bf(v1.y); o[6] = f2bf(v1.z); o[7] = f2bf(v1.w);
    *reinterpret_cast<bf16x8*>(dst + (size_t)off * 8) = o;
}

// 64x64 tile, BK=64, 4 waves x (2x2 fragments x2 k-blocks) of mfma_16x16x32_bf16.
// Epilogue stores clamped tanh(acc+bias) for the tanh-addition identity downstream.
__global__ __launch_bounds__(256) void proj_gemm_bf16(
    const unsigned short* __restrict__ A_bf,   // [320][768]
    const unsigned short* __restrict__ Wp_bf,  // [768][3840]
    const float* __restrict__ bp,
    const unsigned short* __restrict__ Wa_bf,
    const float* __restrict__ ba,
    float* __restrict__ hp,                    // [320][3840] tanh(proj)
    float* __restrict__ ha)
{
    const int which = blockIdx.z;
    const unsigned short* W = which ? Wa_bf : Wp_bf;
    const float* bias       = which ? ba : bp;
    float* out              = which ? ha : hp;

    const int n0 = blockIdx.x * 64;
    const int m0 = blockIdx.y * 64;
    const int tid  = threadIdx.x;
    const int lane = tid & 63;
    const int w    = tid >> 6;

    __shared__ __attribute__((aligned(16))) unsigned short As[64][72]; // [m][k] pad
    __shared__ __attribute__((aligned(16))) unsigned short Bs[64][72]; // [n][k] pad

    f32x4 acc[2][2] = {};

    const int am = tid >> 2;
    const int ak = (tid & 3) * 16;
    const unsigned short* Arow = A_bf + (size_t)(m0 + am) * 768 + ak;

    const int nb = tid & 63;
    const int kt = (tid >> 6) * 16;
    const unsigned short* Wbase = W + (size_t)kt * 3840 + n0 + nb;

    const int wm = (w & 1) * 32;
    const int wn = (w >> 1) * 32;
    const int fr = lane & 15;
    const int fk = (lane >> 4) * 8;

    for (int k0 = 0; k0 < 768; k0 += 64) {
        bf16x8 a0 = *reinterpret_cast<const bf16x8*>(Arow + k0);
        bf16x8 a1 = *reinterpret_cast<const bf16x8*>(Arow + k0 + 8);
        unsigned short bv[16];
        const unsigned short* wp = Wbase + (size_t)k0 * 3840;
        #pragma unroll
        for (int j = 0; j < 16; ++j) bv[j] = wp[(size_t)j * 3840];

        __syncthreads();

        *reinterpret_cast<bf16x8*>(&As[am][ak])     = a0;
        *reinterpret_cast<bf16x8*>(&As[am][ak + 8]) = a1;
        bf16x8 b0, b1;
        #pragma unroll
        for (int j = 0; j < 8; ++j) { b0[j] = (short)bv[j]; b1[j] = (short)bv[8 + j]; }
        *reinterpret_cast<bf16x8*>(&Bs[nb][kt])     = b0;
        *reinterpret_cast<bf16x8*>(&Bs[nb][kt + 8]) = b1;

        __syncthreads();

        #pragma unroll
        for (int kk = 0; kk < 2; ++kk) {
            const int kc = kk * 32 + fk;
            bf16x8 af0 = *reinterpret_cast<const bf16x8*>(&As[wm + fr][kc]);
            bf16x8 af1 = *reinterpret_cast<const bf16x8*>(&As[wm + 16 + fr][kc]);
            bf16x8 bg0 = *reinterpret_cast<const bf16x8*>(&Bs[wn + fr][kc]);
            bf16x8 bg1 = *reinterpret_cast<const bf16x8*>(&Bs[wn + 16 + fr][kc]);
            acc[0][0] = __builtin_amdgcn_mfma_f32_16x16x32_bf16(af0, bg0, acc[0][0], 0, 0, 0);
            acc[0][1] = __builtin_amdgcn_mfma_f32_16x16x32_bf16(af0, bg1, acc[0][1], 0, 0, 0);
            acc[1][0] = __builtin_amdgcn_mfma_f32_16x16x32_bf16(af1, bg0, acc[1][0], 0, 0, 0);
            acc[1][1] = __builtin_amdgcn_mfma_f32_16x16x32_bf16(af1, bg1, acc[1][1], 0, 0, 0);
        }
    }

    // C/D layout: col = lane&15, row = (lane>>4)*4 + reg
    #pragma unroll
    for (int j = 0; j < 2; ++j) {
        const int col = n0 + wn + j * 16 + fr;
        const float bb = bias[col];
        #pragma unroll
        for (int i = 0; i < 2; ++i) {
            #pragma unroll
            for (int r = 0; r < 4; ++r) {
                const int row = m0 + wm + i * 16 + (lane >> 4) * 4 + r;
                float t = tanhf(acc[i][j][r] + bb);
                t = __builtin_amdgcn_fmed3f(t, -0.999999f, 0.999999f);
                out[(size_t)row * 3840 + col] = t;
            }
        }
    }
}

// partial[kq][b,p,c,a] = sum_{h in 96-slice kq} ((tp+ta)/(1+tp*ta))*w  (exact identity)
// 32x32 (p,a) tile, 2x2 per thread, K split x8 across z; plain stores (no atomics).
__global__ __launch_bounds__(256) void scores_partial(
    const float* __restrict__ tp_g,  // [320, 3840]  tanh(hp)
    const float* __restrict__ ta_g,  // [320, 3840]  tanh(ha)
    const float* __restrict__ w_out, // [768]
    float* __restrict__ part_s)      // [8][256000]
{
    const int at0 = blockIdx.x * 32;
    const int pt0 = blockIdx.y * 32;
    const int z   = blockIdx.z;      // 0..79
    const int bc  = z >> 3;
    const int kq  = z & 7;           // 96-wide h slice
    const int b = bc / 5, c = bc % 5;

    const int tid = threadIdx.x;
    const int tx = tid & 15;
    const int ty = tid >> 4;

    __shared__ __attribute__((aligned(16))) float w_s[96];
    __shared__ __attribute__((aligned(16))) float hp_s[32][100]; // 96 + 4 pad
    __shared__ __attribute__((aligned(16))) float ha_s[32][100];

    if (tid < 24) {
        *reinterpret_cast<float4*>(&w_s[tid * 4]) =
            *reinterpret_cast<const float4*>(&w_out[kq * 96 + tid * 4]);
    }

    const float* hp_base = tp_g + (size_t)(b * 160 + pt0) * 3840 + c * 768 + kq * 96;
    const float* ha_base = ta_g + (size_t)(b * 160 + at0) * 3840 + c * 768 + kq * 96;

    #pragma unroll
    for (int i = 0; i < 3; ++i) {
        int f4  = i * 256 + tid;       // 0..767 ; 32 rows x 24 float4
        int row = f4 / 24;
        int col = (f4 % 24) * 4;
        *reinterpret_cast<float4*>(&hp_s[row][col]) =
            *reinterpret_cast<const float4*>(&hp_base[(size_t)row * 3840 + col]);
        *reinterpret_cast<float4*>(&ha_s[row][col]) =
            *reinterpret_cast<const float4*>(&ha_base[(size_t)row * 3840 + col]);
    }
    __syncthreads();

    float acc00 = 0.f, acc01 = 0.f, acc10 = 0.f, acc11 = 0.f;

    #pragma unroll 4
    for (int j = 0; j < 24; ++j) {
        float4 w4 = *reinterpret_cast<const float4*>(&w_s[j * 4]);
        float4 p0 = *reinterpret_cast<const float4*>(&hp_s[ty     ][j * 4]);
        float4 p1 = *reinterpret_cast<const float4*>(&hp_s[ty + 16][j * 4]);
        float4 a0 = *reinterpret_cast<const float4*>(&ha_s[tx     ][j * 4]);
        float4 a1 = *reinterpret_cast<const float4*>(&ha_s[tx + 16][j * 4]);

#define TERM(ACC, P, A, W) \
        { float s_ = (P) + (A); \
          float d_ = fmaf((P), (A), 1.f); \
          ACC = fmaf(s_ * __builtin_amdgcn_rcpf(d_), (W), ACC); }
#define LANE(PX, AX, W) \
        TERM(acc00, p0.PX, a0.AX, W) \
        TERM(acc01, p0.PX, a1.AX, W) \
        TERM(acc10, p1.PX, a0.AX, W) \
        TERM(acc11, p1.PX, a1.AX, W)

        LANE(x, x, w4.x)
        LANE(y, y, w4.y)
        LANE(z, z, w4.z)
        LANE(w, w, w4.w)
#undef LANE
#undef TERM
    }

    float* dst = part_s + (size_t)kq * 256000;
    #pragma unroll
    for (int pi = 0; pi < 2; ++pi) {
        #pragma unroll
        for (int ai = 0; ai < 2; ++ai) {
            const int p = pt0 + pi * 16 + ty;
            const int a = at0 + ai * 16 + tx;
            const size_t idx = ((size_t)(b * 160 + p) * 5 + c) * 160 + a;
            dst[idx] = pi ? (ai ? acc11 : acc10) : (ai ? acc01 : acc00);
        }
    }
}

// one wave per (b,p,c) row: sum 8 partials + mask bias -> write scores to d_out,
// then row log-softmax loss; per-block partial -> part[blk] (NO atomics).
__global__ __launch_bounds__(256) void loss_kernel(
    const float* __restrict__ part_s,  // [8][256000]
    const int*  __restrict__ mask,
    const int*  __restrict__ target,
    float* __restrict__ scores_out,    // [256000] (d_out+1)
    float* __restrict__ part)          // [400][2]
{
    const int lane = threadIdx.x & 63;
    const int wid  = threadIdx.x >> 6;
    const int row  = blockIdx.x * 4 + wid;  // 0..1599
    const size_t base = (size_t)row * 160;

    float x0 = 0.f, x1 = 0.f, x2 = 0.f;
    #pragma unroll
    for (int k = 0; k < 8; ++k) {
        const float* ps = part_s + (size_t)k * 256000 + base;
        x0 += ps[lane];
        x1 += ps[lane + 64];
        if (lane < 32) x2 += ps[lane + 128];
    }
    x0 += mask[base + lane] ? 0.f : -1024.f;
    x1 += mask[base + lane + 64] ? 0.f : -1024.f;
    if (lane < 32) x2 += mask[base + lane + 128] ? 0.f : -1024.f;

    scores_out[base + lane] = x0;
    scores_out[base + lane + 64] = x1;
    if (lane < 32) scores_out[base + lane + 128] = x2;

    float x2r = (lane < 32) ? x2 : -INFINITY;

    float m = fmaxf(fmaxf(x0, x1), x2r);
    #pragma unroll
    for (int o = 32; o >= 1; o >>= 1)
        m = fmaxf(m, __shfl_xor(m, o));

    float s = __expf(x0 - m) + __expf(x1 - m) + ((lane < 32) ? __expf(x2 - m) : 0.f);
    #pragma unroll
    for (int o = 32; o >= 1; o >>= 1)
        s += __shfl_xor(s, o);
    float lse = logf(s) + m;

    const int* t = target + base;
    int t0 = t[lane], t1 = t[lane + 64];
    int t2 = (lane < 32) ? t[lane + 128] : 0;
    float pl = (float)t0 * (lse - x0) + (float)t1 * (lse - x1)
             + ((lane < 32 && t2) ? (float)t2 * (lse - x2) : 0.f);
    float pts = (float)(t0 + t1 + t2);
    #pragma unroll
    for (int o = 32; o >= 1; o >>= 1) {
        pl  += __shfl_xor(pl, o);
        pts += __shfl_xor(pts, o);
    }

    __shared__ float sp[4], st[4];
    if (lane == 0) { sp[wid] = pl; st[wid] = pts; }
    __syncthreads();
    if (threadIdx.x == 0) {
        part[blockIdx.x * 2]     = sp[0] + sp[1] + sp[2] + sp[3];
        part[blockIdx.x * 2 + 1] = st[0] + st[1] + st[2] + st[3];
    }
}

// single block: reduce 400 (pl, pts) pairs -> loss
__global__ __launch_bounds__(256) void finalize_kernel(
    const float* __restrict__ part, float* __restrict__ out0)
{
    const int tid = threadIdx.x;
    float pl = 0.f, pts = 0.f;
    for (int i = tid; i < 400; i += 256) {
        pl  += part[i * 2];
        pts += part[i * 2 + 1];
    }
    #pragma unroll
    for (int o = 32; o >= 1; o >>= 1) {
        pl  += __shfl_xor(pl, o);
        pts += __shfl_xor(pts, o);
    }
    __shared__ float sp[4], st[4];
    const int wid = tid >> 6;
    if ((tid & 63) == 0) { sp[wid] = pl; st[wid] = pts; }
    __syncthreads();
    if (tid == 0) {
        float tl = sp[0] + sp[1] + sp[2] + sp[3];
        float tt = st[0] + st[1] + st[2] + st[3];
        out0[0] = tl / (tt + 1e-6f);
    }
}

extern "C" void kernel_launch(void* const* d_in, const int* in_sizes, int n_in,
                              void* d_out, int out_size, void* d_ws, size_t ws_size,
                              hipStream_t stream) {
    const float* seq   = (const float*)d_in[0];
    const float* w_prd = (const float*)d_in[1];
    const float* b_prd = (const float*)d_in[2];
    const float* w_arg = (const float*)d_in[3];
    const float* b_arg = (const float*)d_in[4];
    const float* w_out = (const float*)d_in[5];
    const int*   mask  = (const int*)d_in[6];
    const int*   targ  = (const int*)d_in[7];

    float* out = (float*)d_out;          // out[0]=loss, out+1 = scores [2,160,5,160]

    char* ws = (char*)d_ws;
    float* hp     = (float*)ws;                      // 320*3840 f32   (4915200 B)
    float* ha     = (float*)(ws + 4915200);          // 320*3840 f32
    float* part_s = (float*)(ws + 9830400);          // 8*256000 f32   (8192000 B)
    float* part   = (float*)(ws + 18022400);         // 400*2 f32      (3200 B)
    unsigned short* A_bf  = (unsigned short*)(ws + 18025600);  // 320*768
    unsigned short* Wp_bf = (unsigned short*)(ws + 18517120);  // 768*3840
    unsigned short* Wa_bf = (unsigned short*)(ws + 24415360);  // 768*3840

    convert_bf16<<<3000, 256, 0, stream>>>(seq, w_prd, w_arg, A_bf, Wp_bf, Wa_bf);

    dim3 g1(60, 5, 2);   // N/64, M/64, {prd,arg}
    proj_gemm_bf16<<<g1, 256, 0, stream>>>(A_bf, Wp_bf, b_prd, Wa_bf, b_arg, hp, ha);

    dim3 g2(5, 5, 80);   // a-tiles(32), p-tiles(32), b*c*k8
    scores_partial<<<g2, 256, 0, stream>>>(hp, ha, w_out, part_s);

    loss_kernel<<<400, 256, 0, stream>>>(part_s, mask, targ, out + 1, part);
    finalize_kernel<<<1, 256, 0, stream>>>(part, out);
}